// Round 8
// baseline (548.110 us; speedup 1.0000x reference)
//
#include <hip/hip_runtime.h>
#include <math.h>

#define EPSF 1e-12f
#define ATT_NORM_F 4.0f
#define H_DIM 8
#define C_DIM 16
#define N_NODES 100000
#define SEG_WORDS (N_NODES * H_DIM)   // 800000 words = 3.2 MB

#define TPB 256
#define NBLK 1024
#define NT (NBLK * TPB)               // 262144 threads
#define ITERS 31                      // ceil(8e6 / 262144)

typedef float v4f __attribute__((ext_vector_type(4)));

// ---------------------------------------------------------------------------
// Zero seg table + 2 barrier words.
// ---------------------------------------------------------------------------
__global__ __launch_bounds__(256) void lip_zero(unsigned* __restrict__ p, int n)
{
    int i = blockIdx.x * 256 + threadIdx.x;
    if (i < n) p[i] = 0u;
}

// ---------------------------------------------------------------------------
// Device-scope grid barrier (validated for correctness in R2 at 1024 blocks).
// ---------------------------------------------------------------------------
__device__ __forceinline__ void grid_barrier(unsigned* bar, unsigned nblk)
{
    __syncthreads();   // drains vmcnt(0): this block's atomics are performed
    if (threadIdx.x == 0) {
        __threadfence();
        unsigned g = __hip_atomic_load(&bar[1], __ATOMIC_RELAXED,
                                       __HIP_MEMORY_SCOPE_AGENT);
        unsigned old = __hip_atomic_fetch_add(&bar[0], 1u, __ATOMIC_ACQ_REL,
                                              __HIP_MEMORY_SCOPE_AGENT);
        if (old == nblk - 1) {
            __hip_atomic_store(&bar[0], 0u, __ATOMIC_RELAXED,
                               __HIP_MEMORY_SCOPE_AGENT);
            __hip_atomic_fetch_add(&bar[1], 1u, __ATOMIC_RELEASE,
                                   __HIP_MEMORY_SCOPE_AGENT);
        } else {
            while (__hip_atomic_load(&bar[1], __ATOMIC_ACQUIRE,
                                     __HIP_MEMORY_SCOPE_AGENT) == g) {
                __builtin_amdgcn_s_sleep(2);
            }
        }
        __threadfence();
    }
    __syncthreads();
}

// ---------------------------------------------------------------------------
// Fused: phase1 streams x (nt), computes per-row norms into LDS, fires
// device atomicMax scatter | grid barrier | phase2 gathers seg with PLAIN
// CACHED loads (nothing cached seg before the barrier -> no staleness; the
// 3.2 MB table becomes L2-hot), combines, writes out (nt).
// Eliminates the 64 MB norm_x HBM round-trip of the 3-dispatch version.
// LDS: 31*256*4 = 31.75 KB/block -> 5 blocks/CU by LDS; launch_bounds(256,4)
// guarantees the 4 blocks/CU co-residency the barrier needs (proven in R2).
// ---------------------------------------------------------------------------
__global__ __launch_bounds__(TPB, 4) void lip_fused(
    const float* __restrict__ x, const float* __restrict__ att_l,
    const float* __restrict__ att_r, const float* __restrict__ alpha,
    const int* __restrict__ index, float* __restrict__ out,
    unsigned* __restrict__ seg, unsigned* __restrict__ bar, int rows)
{
    __shared__ float s_natt[H_DIM];
    __shared__ float s_nrm[ITERS][TPB];

    const int t = threadIdx.x;
    if (t < H_DIM) {
        float s = 0.f;
        #pragma unroll
        for (int c = 0; c < C_DIM; ++c) {
            float l = att_l[t * C_DIM + c];
            float r = att_r[t * C_DIM + c];
            s += l * l + r * r;
        }
        s_natt[t] = ATT_NORM_F * sqrtf(s);
    }
    // s_natt visibility for phase2 is ordered by the barrier's __syncthreads.

    const int tid = blockIdx.x * TPB + t;
    const v4f* x4 = (const v4f*)x;

    #pragma unroll 2
    for (int i = 0; i < ITERS; ++i) {
        int r = tid + i * NT;
        if (r < rows) {
            v4f a = __builtin_nontemporal_load(&x4[(size_t)r * 4 + 0]);
            v4f b = __builtin_nontemporal_load(&x4[(size_t)r * 4 + 1]);
            v4f c = __builtin_nontemporal_load(&x4[(size_t)r * 4 + 2]);
            v4f d = __builtin_nontemporal_load(&x4[(size_t)r * 4 + 3]);
            float s = a.x*a.x + a.y*a.y + a.z*a.z + a.w*a.w
                    + b.x*b.x + b.y*b.y + b.z*b.z + b.w*b.w
                    + c.x*c.x + c.y*c.y + c.z*c.z + c.w*c.w
                    + d.x*d.x + d.y*d.y + d.z*d.z + d.w*d.w;
            s_nrm[i][t] = s;
            int e = r >> 3;
            int h = r & 7;
            // s >= 0: float bits monotone under unsigned max
            atomicMax(&seg[(size_t)index[e] * H_DIM + h], __float_as_uint(s));
        }
    }

    grid_barrier(bar, NBLK);

    #pragma unroll 2
    for (int i = 0; i < ITERS; ++i) {
        int r = tid + i * NT;
        if (r < rows) {
            int e = r >> 3;
            int h = r & 7;
            // plain cached load: final values, L2-hot after first touch
            float sg = __uint_as_float(seg[(size_t)index[e] * H_DIM + h]);
            float al = __builtin_nontemporal_load(&alpha[r]);
            float o  = al / (s_natt[h] * sqrtf(sg + s_nrm[i][t]) + EPSF);
            __builtin_nontemporal_store(o, &out[r]);
        }
    }
}

// ---------------------------------------------------------------------------
// Fallback: proven R4 3-dispatch path (also used if rows > ITERS*NT).
// ---------------------------------------------------------------------------
__global__ __launch_bounds__(256) void lip_pass1(
    const float* __restrict__ x, const int* __restrict__ index,
    float* __restrict__ norm_x, unsigned int* __restrict__ seg, int total)
{
    const int stride = gridDim.x * 256;
    const int s0 = blockIdx.x * 256 + threadIdx.x;
    const int lane = s0 & 3;
    const v4f* x4 = (const v4f*)x;
    #pragma unroll 4
    for (int s = s0; s < total; s += stride) {
        v4f v = __builtin_nontemporal_load(&x4[s]);
        float sum = v.x*v.x + v.y*v.y + v.z*v.z + v.w*v.w;
        sum += __shfl_xor(sum, 1);
        sum += __shfl_xor(sum, 2);
        if (lane == 0) {
            int r = s >> 2;
            __builtin_nontemporal_store(sum, &norm_x[r]);
            int e = r >> 3, h = r & 7;
            atomicMax(&seg[(size_t)index[e] * H_DIM + h], __float_as_uint(sum));
        }
    }
}

__global__ __launch_bounds__(256) void lip_pass2(
    const float* __restrict__ norm_x, const float* __restrict__ alpha,
    const int* __restrict__ index, const unsigned int* __restrict__ seg,
    const float* __restrict__ att_l, const float* __restrict__ att_r,
    float* __restrict__ out, int total)
{
    __shared__ float s_natt[H_DIM];
    int t = threadIdx.x;
    if (t < H_DIM) {
        float s = 0.f;
        #pragma unroll
        for (int c = 0; c < C_DIM; ++c) {
            float l = att_l[t * C_DIM + c];
            float r = att_r[t * C_DIM + c];
            s += l * l + r * r;
        }
        s_natt[t] = ATT_NORM_F * sqrtf(s);
    }
    __syncthreads();

    const int stride = gridDim.x * 256;
    const v4f* nx4 = (const v4f*)norm_x;
    const v4f* al4 = (const v4f*)alpha;
    const v4f* sg4 = (const v4f*)seg;
    v4f* out4 = (v4f*)out;

    #pragma unroll 4
    for (int tid = blockIdx.x * 256 + t; tid < total; tid += stride) {
        int e = tid >> 1;
        int half = tid & 1;
        int idx = index[e];
        v4f nx = nx4[tid];
        v4f al = __builtin_nontemporal_load(&al4[tid]);
        v4f sg = sg4[(size_t)idx * 2 + half];
        int h0 = half * 4;
        v4f o;
        o.x = al.x / (s_natt[h0 + 0] * sqrtf(sg.x + nx.x) + EPSF);
        o.y = al.y / (s_natt[h0 + 1] * sqrtf(sg.y + nx.y) + EPSF);
        o.z = al.z / (s_natt[h0 + 2] * sqrtf(sg.z + nx.z) + EPSF);
        o.w = al.w / (s_natt[h0 + 3] * sqrtf(sg.w + nx.w) + EPSF);
        __builtin_nontemporal_store(o, &out4[tid]);
    }
}

extern "C" void kernel_launch(void* const* d_in, const int* in_sizes, int n_in,
                              void* d_out, int out_size, void* d_ws, size_t ws_size,
                              hipStream_t stream) {
    const float* x     = (const float*)d_in[0];
    const float* att_l = (const float*)d_in[1];
    const float* att_r = (const float*)d_in[2];
    const float* alpha = (const float*)d_in[3];
    const int*   index = (const int*)d_in[4];

    const int E    = in_sizes[4];
    const int rows = E * H_DIM;

    // ws layout: seg[SEG_WORDS] | bar[2]  (| norm_x[rows] for fallback)
    const int zero_words = SEG_WORDS + 2;
    size_t seg_pad = ((size_t)zero_words * 4 + 255) / 256 * 256;
    size_t need_fb = seg_pad + (size_t)rows * 4;

    unsigned* seg = (unsigned*)d_ws;
    unsigned* bar = seg + SEG_WORDS;

    if (rows <= ITERS * NT && ws_size >= (size_t)zero_words * 4) {
        lip_zero<<<(zero_words + 255) / 256, 256, 0, stream>>>(seg, zero_words);
        lip_fused<<<NBLK, TPB, 0, stream>>>(
            x, att_l, att_r, alpha, index, (float*)d_out, seg, bar, rows);
    } else {
        float* norm_x = (float*)((char*)d_ws + seg_pad);
        lip_zero<<<(SEG_WORDS + 255) / 256, 256, 0, stream>>>(seg, SEG_WORDS);
        lip_pass1<<<2048, 256, 0, stream>>>(x, index, norm_x, seg, rows * 4);
        lip_pass2<<<2048, 256, 0, stream>>>(
            norm_x, alpha, index, seg, att_l, att_r, (float*)d_out, E * 2);
        (void)need_fb;
    }
}

// Round 9
// 138.429 us; speedup vs baseline: 3.9595x; 3.9595x over previous
//
#include <hip/hip_runtime.h>
#include <math.h>

#define EPSF 1e-12f
#define ATT_NORM_F 4.0f
#define H_DIM 8
#define C_DIM 16
#define N_NODES 100000
#define SEG_WORDS (N_NODES * H_DIM)   // 800000 words = 3.2 MB

typedef float v4f __attribute__((ext_vector_type(4)));

// ---------------------------------------------------------------------------
// Zero the seg table.
// ---------------------------------------------------------------------------
__global__ __launch_bounds__(256) void lip_zero(unsigned* __restrict__ p, int n)
{
    int i = blockIdx.x * 256 + threadIdx.x;
    if (i < n) p[i] = 0u;
}

// ---------------------------------------------------------------------------
// Pass 1 (grid-stride, 2048 blocks): norm_x[r] = sum_c x[r,c]^2 ; device
// atomicMax scatter into seg (fire-and-forget, overlapped with the stream).
// 4 lanes per (e,h) row -> each wave load instruction covers 1 KB contiguous.
// x is nt (zero reuse); norm_x uses a REGULAR store so the 32 MB can stay
// in LLC for pass2 (R4 nt-stored it and paid an HBM re-fetch).
// ---------------------------------------------------------------------------
__global__ __launch_bounds__(256) void lip_pass1(
    const float* __restrict__ x, const int* __restrict__ index,
    float* __restrict__ norm_x, unsigned int* __restrict__ seg, int total /*rows*4*/)
{
    const int stride = gridDim.x * 256;
    const int s0 = blockIdx.x * 256 + threadIdx.x;
    const int lane = s0 & 3;                 // stride % 4 == 0 -> constant
    const v4f* x4 = (const v4f*)x;

    #pragma unroll 4
    for (int s = s0; s < total; s += stride) {
        v4f v = __builtin_nontemporal_load(&x4[s]);
        float sum = v.x * v.x + v.y * v.y + v.z * v.z + v.w * v.w;
        sum += __shfl_xor(sum, 1);
        sum += __shfl_xor(sum, 2);
        if (lane == 0) {
            int r = s >> 2;
            norm_x[r] = sum;                 // cache-allocating -> LLC for pass2
            int e = r >> 3;
            int h = r & 7;
            // sum >= 0: float bits monotone under unsigned max
            atomicMax(&seg[(size_t)index[e] * H_DIM + h], __float_as_uint(sum));
        }
    }
}

// ---------------------------------------------------------------------------
// Pass 2 (one-shot): out = alpha / (natt * sqrt(seg[idx] + norm_x) + eps)
// One thread per 4 consecutive heads (float4 everywhere). seg gather is
// L2-resident (3.2 MB); norm_x is expected LLC-hot; alpha/out are nt streams.
// ---------------------------------------------------------------------------
__global__ __launch_bounds__(256) void lip_pass2(
    const float* __restrict__ norm_x, const float* __restrict__ alpha,
    const int* __restrict__ index, const unsigned int* __restrict__ seg,
    const float* __restrict__ att_l, const float* __restrict__ att_r,
    float* __restrict__ out, int total)   // total = E*2
{
    __shared__ float s_natt[H_DIM];
    int t = threadIdx.x;
    if (t < H_DIM) {
        float s = 0.f;
        #pragma unroll
        for (int c = 0; c < C_DIM; ++c) {
            float l = att_l[t * C_DIM + c];
            float r = att_r[t * C_DIM + c];
            s += l * l + r * r;
        }
        s_natt[t] = ATT_NORM_F * sqrtf(s);
    }
    __syncthreads();

    int tid = blockIdx.x * 256 + t;
    if (tid >= total) return;

    int e    = tid >> 1;
    int half = tid & 1;
    int idx  = index[e];

    const v4f* nx4 = (const v4f*)norm_x;
    const v4f* al4 = (const v4f*)alpha;
    const v4f* sg4 = (const v4f*)seg;       // bits are non-negative floats

    v4f nx = nx4[tid];                               // LLC-hot (pass1 wrote it)
    v4f al = __builtin_nontemporal_load(&al4[tid]);  // cold stream
    v4f sg = sg4[(size_t)idx * 2 + half];            // L2-resident gather

    int h0 = half * 4;
    v4f o;
    o.x = al.x / (s_natt[h0 + 0] * sqrtf(sg.x + nx.x) + EPSF);
    o.y = al.y / (s_natt[h0 + 1] * sqrtf(sg.y + nx.y) + EPSF);
    o.z = al.z / (s_natt[h0 + 2] * sqrtf(sg.z + nx.z) + EPSF);
    o.w = al.w / (s_natt[h0 + 3] * sqrtf(sg.w + nx.w) + EPSF);
    __builtin_nontemporal_store(o, &((v4f*)out)[tid]);
}

// ---------------------------------------------------------------------------
// Fallback pass 2 (no norm_x buffer): recompute norm from x.
// ---------------------------------------------------------------------------
__global__ __launch_bounds__(256) void lip_pass2_recompute(
    const float* __restrict__ x, const float* __restrict__ alpha,
    const int* __restrict__ index, const unsigned int* __restrict__ seg,
    const float* __restrict__ att_l, const float* __restrict__ att_r,
    float* __restrict__ out, int rows)
{
    __shared__ float s_natt[H_DIM];
    int t = threadIdx.x;
    if (t < H_DIM) {
        float s = 0.f;
        #pragma unroll
        for (int c = 0; c < C_DIM; ++c) {
            float l = att_l[t * C_DIM + c];
            float r = att_r[t * C_DIM + c];
            s += l * l + r * r;
        }
        s_natt[t] = ATT_NORM_F * sqrtf(s);
    }
    __syncthreads();

    int r = blockIdx.x * blockDim.x + t;
    if (r >= rows) return;

    const float4* x4 = (const float4*)x;
    float s = 0.f;
    #pragma unroll
    for (int q = 0; q < 4; ++q) {
        float4 v = x4[(size_t)r * 4 + q];
        s += v.x * v.x + v.y * v.y + v.z * v.z + v.w * v.w;
    }
    int e = r >> 3;
    int h = r & 7;
    float sg = __uint_as_float(seg[(size_t)index[e] * H_DIM + h]);
    out[r] = alpha[r] / (s_natt[h] * sqrtf(sg + s) + EPSF);
}

// Pass 1 merged fallback (used only if ws can't hold norm_x).
__global__ __launch_bounds__(256) void lip_pass1_merged(
    const float* __restrict__ x, const int* __restrict__ index,
    unsigned int* __restrict__ seg, int total /*rows*4*/)
{
    const int stride = gridDim.x * 256;
    const int s0 = blockIdx.x * 256 + threadIdx.x;
    const int lane = s0 & 3;
    const v4f* x4 = (const v4f*)x;
    #pragma unroll 4
    for (int s = s0; s < total; s += stride) {
        v4f v = __builtin_nontemporal_load(&x4[s]);
        float sum = v.x * v.x + v.y * v.y + v.z * v.z + v.w * v.w;
        sum += __shfl_xor(sum, 1);
        sum += __shfl_xor(sum, 2);
        if (lane == 0) {
            int r = s >> 2;
            int e = r >> 3, h = r & 7;
            atomicMax(&seg[(size_t)index[e] * H_DIM + h], __float_as_uint(sum));
        }
    }
}

extern "C" void kernel_launch(void* const* d_in, const int* in_sizes, int n_in,
                              void* d_out, int out_size, void* d_ws, size_t ws_size,
                              hipStream_t stream) {
    const float* x     = (const float*)d_in[0];
    const float* att_l = (const float*)d_in[1];
    const float* att_r = (const float*)d_in[2];
    const float* alpha = (const float*)d_in[3];
    const int*   index = (const int*)d_in[4];

    const int E    = in_sizes[4];
    const int rows = E * H_DIM;

    size_t seg_pad = ((size_t)SEG_WORDS * 4 + 255) / 256 * 256;
    size_t need    = seg_pad + (size_t)rows * sizeof(float);

    unsigned* seg = (unsigned*)d_ws;
    lip_zero<<<(SEG_WORDS + 255) / 256, 256, 0, stream>>>(seg, SEG_WORDS);

    if (ws_size >= need) {
        float* norm_x = (float*)((char*)d_ws + seg_pad);
        lip_pass1<<<2048, 256, 0, stream>>>(x, index, norm_x, seg, rows * 4);
        int t2 = E * 2;
        lip_pass2<<<(t2 + 255) / 256, 256, 0, stream>>>(
            norm_x, alpha, index, seg, att_l, att_r, (float*)d_out, t2);
    } else {
        lip_pass1_merged<<<2048, 256, 0, stream>>>(x, index, seg, rows * 4);
        lip_pass2_recompute<<<(rows + 255) / 256, 256, 0, stream>>>(
            x, alpha, index, seg, att_l, att_r, (float*)d_out, rows);
    }
}

// Round 10
// 132.000 us; speedup vs baseline: 4.1523x; 1.0487x over previous
//
#include <hip/hip_runtime.h>
#include <math.h>

#define EPSF 1e-12f
#define ATT_NORM_F 4.0f
#define H_DIM 8
#define C_DIM 16
#define N_NODES 100000
#define SEG_WORDS (N_NODES * H_DIM)   // 800000 words = 3.2 MB

#define CHUNK 192                     // rows per phase per block (= 3*64)
#define PASSES 4                      // row-passes per phase (48 rows each)

typedef float v4f __attribute__((ext_vector_type(4)));

// ---------------------------------------------------------------------------
// Zero the seg table.
// ---------------------------------------------------------------------------
__global__ __launch_bounds__(256) void lip_zero(unsigned* __restrict__ p, int n)
{
    int i = blockIdx.x * 256 + threadIdx.x;
    if (i < n) p[i] = 0u;
}

// ---------------------------------------------------------------------------
// Pass 1, producer/consumer: waves 0-2 stream x and compute row norms into a
// double-buffered LDS chunk; wave 3 alone fires the atomicMax scatter.
// Rationale (vmcnt is in-order): interleaving slow fabric RMWs into the
// streaming wave's VMEM queue stalls every subsequent load-consume behind
// them. Splitting roles keeps streamer queues atomic-free; the scatter
// wave's queue is fire-and-forget (no dependent consumption) and only
// drains at the per-phase barrier (~4 us apart >> atomic latency).
// Pipeline: phase p streams chunk c(p) into buf[p&1] while scattering
// chunk c(p-1) from buf[(p-1)&1]; one __syncthreads per phase.
// ---------------------------------------------------------------------------
__global__ __launch_bounds__(256) void lip_pass1_pc(
    const float* __restrict__ x, const int* __restrict__ index,
    float* __restrict__ norm_x, unsigned* __restrict__ seg, int rows)
{
    __shared__ float buf[2][CHUNK];

    const int t = threadIdx.x;
    const int w = t >> 6;                     // wave id 0..3
    const int nchunks = (rows + CHUNK - 1) / CHUNK;
    const v4f* x4 = (const v4f*)x;

    const int rloc = t >> 2;                  // 0..47 (valid for w<3)
    const int lane = t & 3;

    for (int p = 0; ; ++p) {
        int c  = blockIdx.x + p * gridDim.x;          // chunk to stream
        int cp = c - gridDim.x;                       // chunk to scatter
        bool do_s = (c < nchunks);
        bool do_a = (p > 0) && (cp < nchunks);
        if (!do_s && !do_a) break;                    // block-uniform exit

        if (w < 3) {
            if (do_s) {
                int base = c * CHUNK;
                float* b = buf[p & 1];
                #pragma unroll
                for (int j = 0; j < PASSES; ++j) {
                    int r = base + j * 48 + rloc;
                    if (r < rows) {
                        v4f v = __builtin_nontemporal_load(&x4[(size_t)r * 4 + lane]);
                        float s = v.x * v.x + v.y * v.y + v.z * v.z + v.w * v.w;
                        s += __shfl_xor(s, 1);
                        s += __shfl_xor(s, 2);
                        if (lane == 0) {
                            // 16 lane0s per wave -> 64B contiguous sector
                            __builtin_nontemporal_store(s, &norm_x[r]);
                            b[j * 48 + rloc] = s;
                        }
                    }
                }
            }
        } else {
            if (do_a) {
                int base = cp * CHUNK;
                const float* b = buf[(p & 1) ^ 1];
                int ln = t & 63;
                #pragma unroll
                for (int k = 0; k < 3; ++k) {
                    int i = k * 64 + ln;              // 0..191
                    int r = base + i;
                    if (r < rows) {
                        float s = b[i];
                        int e = r >> 3;
                        int h = r & 7;
                        // s >= 0: float bits monotone under unsigned max
                        atomicMax(&seg[(size_t)index[e] * H_DIM + h],
                                  __float_as_uint(s));
                    }
                }
            }
        }
        __syncthreads();   // publishes buf[p&1]; confirms buf[(p-1)&1] drained
    }
}

// ---------------------------------------------------------------------------
// Pass 2 (one-shot): out = alpha / (natt * sqrt(seg[idx] + norm_x) + eps)
// One thread per 4 consecutive heads (float4 everywhere). seg gather is
// L2-resident; norm_x is LLC-hot (pass1 cache-allocating store); alpha/out nt.
// ---------------------------------------------------------------------------
__global__ __launch_bounds__(256) void lip_pass2(
    const float* __restrict__ norm_x, const float* __restrict__ alpha,
    const int* __restrict__ index, const unsigned int* __restrict__ seg,
    const float* __restrict__ att_l, const float* __restrict__ att_r,
    float* __restrict__ out, int total)   // total = E*2
{
    __shared__ float s_natt[H_DIM];
    int t = threadIdx.x;
    if (t < H_DIM) {
        float s = 0.f;
        #pragma unroll
        for (int c = 0; c < C_DIM; ++c) {
            float l = att_l[t * C_DIM + c];
            float r = att_r[t * C_DIM + c];
            s += l * l + r * r;
        }
        s_natt[t] = ATT_NORM_F * sqrtf(s);
    }
    __syncthreads();

    int tid = blockIdx.x * 256 + t;
    if (tid >= total) return;

    int e    = tid >> 1;
    int half = tid & 1;
    int idx  = index[e];

    const v4f* nx4 = (const v4f*)norm_x;
    const v4f* al4 = (const v4f*)alpha;
    const v4f* sg4 = (const v4f*)seg;       // bits are non-negative floats

    v4f nx = nx4[tid];                               // LLC-hot
    v4f al = __builtin_nontemporal_load(&al4[tid]);  // cold stream
    v4f sg = sg4[(size_t)idx * 2 + half];            // L2-resident gather

    int h0 = half * 4;
    v4f o;
    o.x = al.x / (s_natt[h0 + 0] * sqrtf(sg.x + nx.x) + EPSF);
    o.y = al.y / (s_natt[h0 + 1] * sqrtf(sg.y + nx.y) + EPSF);
    o.z = al.z / (s_natt[h0 + 2] * sqrtf(sg.z + nx.z) + EPSF);
    o.w = al.w / (s_natt[h0 + 3] * sqrtf(sg.w + nx.w) + EPSF);
    __builtin_nontemporal_store(o, &((v4f*)out)[tid]);
}

// ---------------------------------------------------------------------------
// Fallbacks (ws too small): merged pass1 + recompute pass2 (R4-style).
// ---------------------------------------------------------------------------
__global__ __launch_bounds__(256) void lip_pass1_merged(
    const float* __restrict__ x, const int* __restrict__ index,
    unsigned int* __restrict__ seg, int total /*rows*4*/)
{
    const int stride = gridDim.x * 256;
    const int s0 = blockIdx.x * 256 + threadIdx.x;
    const int lane = s0 & 3;
    const v4f* x4 = (const v4f*)x;
    #pragma unroll 4
    for (int s = s0; s < total; s += stride) {
        v4f v = __builtin_nontemporal_load(&x4[s]);
        float sum = v.x * v.x + v.y * v.y + v.z * v.z + v.w * v.w;
        sum += __shfl_xor(sum, 1);
        sum += __shfl_xor(sum, 2);
        if (lane == 0) {
            int r = s >> 2;
            int e = r >> 3, h = r & 7;
            atomicMax(&seg[(size_t)index[e] * H_DIM + h], __float_as_uint(sum));
        }
    }
}

__global__ __launch_bounds__(256) void lip_pass2_recompute(
    const float* __restrict__ x, const float* __restrict__ alpha,
    const int* __restrict__ index, const unsigned int* __restrict__ seg,
    const float* __restrict__ att_l, const float* __restrict__ att_r,
    float* __restrict__ out, int rows)
{
    __shared__ float s_natt[H_DIM];
    int t = threadIdx.x;
    if (t < H_DIM) {
        float s = 0.f;
        #pragma unroll
        for (int c = 0; c < C_DIM; ++c) {
            float l = att_l[t * C_DIM + c];
            float r = att_r[t * C_DIM + c];
            s += l * l + r * r;
        }
        s_natt[t] = ATT_NORM_F * sqrtf(s);
    }
    __syncthreads();

    int r = blockIdx.x * blockDim.x + t;
    if (r >= rows) return;

    const float4* x4 = (const float4*)x;
    float s = 0.f;
    #pragma unroll
    for (int q = 0; q < 4; ++q) {
        float4 v = x4[(size_t)r * 4 + q];
        s += v.x * v.x + v.y * v.y + v.z * v.z + v.w * v.w;
    }
    int e = r >> 3;
    int h = r & 7;
    float sg = __uint_as_float(seg[(size_t)index[e] * H_DIM + h]);
    out[r] = alpha[r] / (s_natt[h] * sqrtf(sg + s) + EPSF);
}

extern "C" void kernel_launch(void* const* d_in, const int* in_sizes, int n_in,
                              void* d_out, int out_size, void* d_ws, size_t ws_size,
                              hipStream_t stream) {
    const float* x     = (const float*)d_in[0];
    const float* att_l = (const float*)d_in[1];
    const float* att_r = (const float*)d_in[2];
    const float* alpha = (const float*)d_in[3];
    const int*   index = (const int*)d_in[4];

    const int E    = in_sizes[4];
    const int rows = E * H_DIM;

    size_t seg_pad = ((size_t)SEG_WORDS * 4 + 255) / 256 * 256;
    size_t need    = seg_pad + (size_t)rows * sizeof(float);

    unsigned* seg = (unsigned*)d_ws;
    lip_zero<<<(SEG_WORDS + 255) / 256, 256, 0, stream>>>(seg, SEG_WORDS);

    if (ws_size >= need) {
        float* norm_x = (float*)((char*)d_ws + seg_pad);
        lip_pass1_pc<<<2048, 256, 0, stream>>>(x, index, norm_x, seg, rows);
        int t2 = E * 2;
        lip_pass2<<<(t2 + 255) / 256, 256, 0, stream>>>(
            norm_x, alpha, index, seg, att_l, att_r, (float*)d_out, t2);
    } else {
        lip_pass1_merged<<<2048, 256, 0, stream>>>(x, index, seg, rows * 4);
        lip_pass2_recompute<<<(rows + 255) / 256, 256, 0, stream>>>(
            x, alpha, index, seg, att_l, att_r, (float*)d_out, rows);
    }
}

// Round 11
// 129.978 us; speedup vs baseline: 4.2169x; 1.0156x over previous
//
#include <hip/hip_runtime.h>
#include <math.h>

#define EPSF 1e-12f
#define ATT_NORM_F 4.0f
#define H_DIM 8
#define C_DIM 16
#define N_NODES 100000
#define SEG_WORDS (N_NODES * H_DIM)   // 800000 words = 3.2 MB

#define CHUNK 192                     // rows per phase per block (= 3*64)
#define PASSES 4                      // row-passes per phase (48 rows each)

typedef float v4f __attribute__((ext_vector_type(4)));

// ---------------------------------------------------------------------------
// Zero the seg table.
// ---------------------------------------------------------------------------
__global__ __launch_bounds__(256) void lip_zero(unsigned* __restrict__ p, int n)
{
    int i = blockIdx.x * 256 + threadIdx.x;
    if (i < n) p[i] = 0u;
}

// ---------------------------------------------------------------------------
// LDS-only barrier: __syncthreads() lowers to s_waitcnt vmcnt(0) lgkmcnt(0)
// + s_barrier, which force-drains every wave's VMEM queue each phase
// (streamers wait on nt-loads/stores; the scatter wave waits on ~192
// in-flight fabric atomics). The ONLY cross-wave dependency here is LDS
// produce/consume, which lgkmcnt(0) covers. Keep vmem in flight.
// ---------------------------------------------------------------------------
__device__ __forceinline__ void lds_barrier()
{
    asm volatile("s_waitcnt lgkmcnt(0)\n\ts_barrier" ::: "memory");
}

// ---------------------------------------------------------------------------
// Pass 1, producer/consumer: waves 0-2 stream x and compute row norms into a
// double-buffered LDS chunk; wave 3 alone fires the atomicMax scatter.
// Streamer vmcnt queues stay atomic-free (no in-order retire stalls);
// scatter-wave atomics are fire-and-forget and now NEVER drained mid-kernel
// (lds_barrier waits lgkmcnt only; hw vmcnt queue depth throttles at 63).
// norm_x uses a REGULAR store so the 32 MB stays LLC-resident for pass2.
// ---------------------------------------------------------------------------
__global__ __launch_bounds__(256) void lip_pass1_pc(
    const float* __restrict__ x, const int* __restrict__ index,
    float* __restrict__ norm_x, unsigned* __restrict__ seg, int rows)
{
    __shared__ float buf[2][CHUNK];

    const int t = threadIdx.x;
    const int w = t >> 6;                     // wave id 0..3
    const int nchunks = (rows + CHUNK - 1) / CHUNK;
    const v4f* x4 = (const v4f*)x;

    const int rloc = t >> 2;                  // 0..47 (valid for w<3)
    const int lane = t & 3;

    for (int p = 0; ; ++p) {
        int c  = blockIdx.x + p * gridDim.x;          // chunk to stream
        int cp = c - gridDim.x;                       // chunk to scatter
        bool do_s = (c < nchunks);
        bool do_a = (p > 0) && (cp < nchunks);
        if (!do_s && !do_a) break;                    // block-uniform exit

        if (w < 3) {
            if (do_s) {
                int base = c * CHUNK;
                float* b = buf[p & 1];
                #pragma unroll
                for (int j = 0; j < PASSES; ++j) {
                    int r = base + j * 48 + rloc;
                    if (r < rows) {
                        v4f v = __builtin_nontemporal_load(&x4[(size_t)r * 4 + lane]);
                        float s = v.x * v.x + v.y * v.y + v.z * v.z + v.w * v.w;
                        s += __shfl_xor(s, 1);
                        s += __shfl_xor(s, 2);
                        if (lane == 0) {
                            norm_x[r] = s;    // cache-allocating -> LLC for pass2
                            b[j * 48 + rloc] = s;
                        }
                    }
                }
            }
        } else {
            if (do_a) {
                int base = cp * CHUNK;
                const float* b = buf[(p & 1) ^ 1];
                int ln = t & 63;
                #pragma unroll
                for (int k = 0; k < 3; ++k) {
                    int i = k * 64 + ln;              // 0..191
                    int r = base + i;
                    if (r < rows) {
                        float s = b[i];
                        int e = r >> 3;
                        int h = r & 7;
                        // s >= 0: float bits monotone under unsigned max
                        atomicMax(&seg[(size_t)index[e] * H_DIM + h],
                                  __float_as_uint(s));
                    }
                }
            }
        }
        lds_barrier();   // publishes buf[p&1]; confirms buf[(p-1)&1] drained
    }
}

// ---------------------------------------------------------------------------
// Pass 2 (one-shot): out = alpha / (natt * sqrt(seg[idx] + norm_x) + eps)
// One thread per 4 consecutive heads (float4 everywhere). seg gather is
// L2-resident; norm_x is LLC-hot (pass1 cache-allocating store); alpha/out nt.
// ---------------------------------------------------------------------------
__global__ __launch_bounds__(256) void lip_pass2(
    const float* __restrict__ norm_x, const float* __restrict__ alpha,
    const int* __restrict__ index, const unsigned int* __restrict__ seg,
    const float* __restrict__ att_l, const float* __restrict__ att_r,
    float* __restrict__ out, int total)   // total = E*2
{
    __shared__ float s_natt[H_DIM];
    int t = threadIdx.x;
    if (t < H_DIM) {
        float s = 0.f;
        #pragma unroll
        for (int c = 0; c < C_DIM; ++c) {
            float l = att_l[t * C_DIM + c];
            float r = att_r[t * C_DIM + c];
            s += l * l + r * r;
        }
        s_natt[t] = ATT_NORM_F * sqrtf(s);
    }
    __syncthreads();

    int tid = blockIdx.x * 256 + t;
    if (tid >= total) return;

    int e    = tid >> 1;
    int half = tid & 1;
    int idx  = index[e];

    const v4f* nx4 = (const v4f*)norm_x;
    const v4f* al4 = (const v4f*)alpha;
    const v4f* sg4 = (const v4f*)seg;       // bits are non-negative floats

    v4f nx = nx4[tid];                               // LLC-hot
    v4f al = __builtin_nontemporal_load(&al4[tid]);  // cold stream
    v4f sg = sg4[(size_t)idx * 2 + half];            // L2-resident gather

    int h0 = half * 4;
    v4f o;
    o.x = al.x / (s_natt[h0 + 0] * sqrtf(sg.x + nx.x) + EPSF);
    o.y = al.y / (s_natt[h0 + 1] * sqrtf(sg.y + nx.y) + EPSF);
    o.z = al.z / (s_natt[h0 + 2] * sqrtf(sg.z + nx.z) + EPSF);
    o.w = al.w / (s_natt[h0 + 3] * sqrtf(sg.w + nx.w) + EPSF);
    __builtin_nontemporal_store(o, &((v4f*)out)[tid]);
}

// ---------------------------------------------------------------------------
// Fallbacks (ws too small): merged pass1 + recompute pass2 (R4-style).
// ---------------------------------------------------------------------------
__global__ __launch_bounds__(256) void lip_pass1_merged(
    const float* __restrict__ x, const int* __restrict__ index,
    unsigned int* __restrict__ seg, int total /*rows*4*/)
{
    const int stride = gridDim.x * 256;
    const int s0 = blockIdx.x * 256 + threadIdx.x;
    const int lane = s0 & 3;
    const v4f* x4 = (const v4f*)x;
    #pragma unroll 4
    for (int s = s0; s < total; s += stride) {
        v4f v = __builtin_nontemporal_load(&x4[s]);
        float sum = v.x * v.x + v.y * v.y + v.z * v.z + v.w * v.w;
        sum += __shfl_xor(sum, 1);
        sum += __shfl_xor(sum, 2);
        if (lane == 0) {
            int r = s >> 2;
            int e = r >> 3, h = r & 7;
            atomicMax(&seg[(size_t)index[e] * H_DIM + h], __float_as_uint(sum));
        }
    }
}

__global__ __launch_bounds__(256) void lip_pass2_recompute(
    const float* __restrict__ x, const float* __restrict__ alpha,
    const int* __restrict__ index, const unsigned int* __restrict__ seg,
    const float* __restrict__ att_l, const float* __restrict__ att_r,
    float* __restrict__ out, int rows)
{
    __shared__ float s_natt[H_DIM];
    int t = threadIdx.x;
    if (t < H_DIM) {
        float s = 0.f;
        #pragma unroll
        for (int c = 0; c < C_DIM; ++c) {
            float l = att_l[t * C_DIM + c];
            float r = att_r[t * C_DIM + c];
            s += l * l + r * r;
        }
        s_natt[t] = ATT_NORM_F * sqrtf(s);
    }
    __syncthreads();

    int r = blockIdx.x * blockDim.x + t;
    if (r >= rows) return;

    const float4* x4 = (const float4*)x;
    float s = 0.f;
    #pragma unroll
    for (int q = 0; q < 4; ++q) {
        float4 v = x4[(size_t)r * 4 + q];
        s += v.x * v.x + v.y * v.y + v.z * v.z + v.w * v.w;
    }
    int e = r >> 3;
    int h = r & 7;
    float sg = __uint_as_float(seg[(size_t)index[e] * H_DIM + h]);
    out[r] = alpha[r] / (s_natt[h] * sqrtf(sg + s) + EPSF);
}

extern "C" void kernel_launch(void* const* d_in, const int* in_sizes, int n_in,
                              void* d_out, int out_size, void* d_ws, size_t ws_size,
                              hipStream_t stream) {
    const float* x     = (const float*)d_in[0];
    const float* att_l = (const float*)d_in[1];
    const float* att_r = (const float*)d_in[2];
    const float* alpha = (const float*)d_in[3];
    const int*   index = (const int*)d_in[4];

    const int E    = in_sizes[4];
    const int rows = E * H_DIM;

    size_t seg_pad = ((size_t)SEG_WORDS * 4 + 255) / 256 * 256;
    size_t need    = seg_pad + (size_t)rows * sizeof(float);

    unsigned* seg = (unsigned*)d_ws;
    lip_zero<<<(SEG_WORDS + 255) / 256, 256, 0, stream>>>(seg, SEG_WORDS);

    if (ws_size >= need) {
        float* norm_x = (float*)((char*)d_ws + seg_pad);
        lip_pass1_pc<<<2048, 256, 0, stream>>>(x, index, norm_x, seg, rows);
        int t2 = E * 2;
        lip_pass2<<<(t2 + 255) / 256, 256, 0, stream>>>(
            norm_x, alpha, index, seg, att_l, att_r, (float*)d_out, t2);
    } else {
        lip_pass1_merged<<<2048, 256, 0, stream>>>(x, index, seg, rows * 4);
        lip_pass2_recompute<<<(rows + 255) / 256, 256, 0, stream>>>(
            x, alpha, index, seg, att_l, att_r, (float*)d_out, rows);
    }
}